// Round 1
// baseline (486.371 us; speedup 1.0000x reference)
//
#include <hip/hip_runtime.h>
#include <math.h>

#define HH   96
#define WW   96
#define HWSZ 9216
#define CCH  64
#define KK   16
#define QQ   32768
#define BB   2
#define HIDN 64

// ---------------------------------------------------------------------------
// K1: 3x3 SAME conv (NCHW, OIHW) -> feat_t [B*HW][64]  (channel-contiguous for gathers)
// ---------------------------------------------------------------------------
__global__ __launch_bounds__(256) void conv_kernel(
    const float* __restrict__ inp, const float* __restrict__ w_enc,
    const float* __restrict__ b_enc, float* __restrict__ feat_t)
{
    int idx = blockIdx.x * 256 + threadIdx.x;      // < B*HW*64
    int c   = idx & 63;
    int p   = idx >> 6;                            // b*HW + pix
    int b   = p / HWSZ;
    int pix = p - b * HWSZ;
    int y   = pix / WW;
    int x   = pix - y * WW;
    float acc = b_enc[c];
    #pragma unroll
    for (int ci = 0; ci < 3; ci++) {
        #pragma unroll
        for (int ky = 0; ky < 3; ky++) {
            int yy = y + ky - 1;
            if (yy < 0 || yy >= HH) continue;
            #pragma unroll
            for (int kx = 0; kx < 3; kx++) {
                int xx = x + kx - 1;
                if (xx < 0 || xx >= WW) continue;
                acc = fmaf(inp[((b * 3 + ci) * HH + yy) * WW + xx],
                           w_enc[((c * 3 + ci) * 3 + ky) * 3 + kx], acc);
            }
        }
    }
    feat_t[idx] = acc;
}

// ---------------------------------------------------------------------------
// K1b: transpose w_m2 [64][c*16+k] -> w_m2t [64][k*64+c];  b_m2 likewise
// ---------------------------------------------------------------------------
__global__ __launch_bounds__(256) void transpose_w2(
    const float* __restrict__ w_m2, const float* __restrict__ b_m2,
    float* __restrict__ w_m2t, float* __restrict__ b_m2t)
{
    int t = blockIdx.x * 256 + threadIdx.x;
    if (t < 65536) {
        int h = t >> 10, kc = t & 1023, k = kc >> 6, c = kc & 63;
        w_m2t[t] = w_m2[h * 1024 + c * 16 + k];
    } else if (t < 66560) {
        int kc = t - 65536, k = kc >> 6, c = kc & 63;
        b_m2t[kc] = b_m2[c * 16 + k];
    }
}

// ---------------------------------------------------------------------------
// K2: per-query prep (indices, rel, weights) + meta MLP layer 1 (33->64, relu)
// one wave per query; 4 waves / block
// ---------------------------------------------------------------------------
__global__ __launch_bounds__(256) void prep_kernel(
    const float* __restrict__ coord, const float* __restrict__ cell,
    const float* __restrict__ w_m1, const float* __restrict__ b_m1,
    float* __restrict__ h_ws, int* __restrict__ pix_ws,
    float* __restrict__ rel0_ws, float* __restrict__ rel1_ws,
    float* __restrict__ wgt_ws)
{
    #pragma clang fp contract(off)   // index path must round like the JAX reference
    __shared__ float mi[4][34];
    int t    = threadIdx.x;
    int wv   = t >> 6;
    int lane = t & 63;
    int q0   = blockIdx.x * 4 + wv;        // global query id in [0, B*Q)

    float c0 = coord[q0 * 2 + 0];
    float c1 = coord[q0 * 2 + 1];
    int   k  = lane & 15;
    float vx = 2.0f * (float)(k >> 2) - 3.0f;   // v = {-3,-1,1,3}, vx outer
    float vy = 2.0f * (float)(k & 3) - 3.0f;    // vy inner
    const float r  = 1.0f / 96.0f;
    const float LO = (float)(-1.0 + 1e-6);
    const float HI = (float)( 1.0 - 1e-6);

    float cs0 = (c0 + vx * r) + 1e-6f;
    float cs1 = (c1 + vy * r) + 1e-6f;
    cs0 = fminf(fmaxf(cs0, LO), HI);
    cs1 = fminf(fmaxf(cs1, LO), HI);

    // pix = (c+1)*size/2 - 0.5, round half-to-even (rintf), clip
    float fy = (cs0 + 1.0f) * 48.0f - 0.5f;
    float fx = (cs1 + 1.0f) * 48.0f - 0.5f;
    int iy = (int)rintf(fy);  iy = min(max(iy, 0), 95);
    int ix = (int)rintf(fx);  ix = min(max(ix, 0), 95);
    int pix = iy * 96 + ix;

    float qcy = -1.0f + (2.0f * (float)iy + 1.0f) / 96.0f;
    float qcx = -1.0f + (2.0f * (float)ix + 1.0f) / 96.0f;
    float rel0 = (c0 - qcy) * 96.0f;
    float rel1 = (c1 - qcx) * 96.0f;
    float area = fabsf(rel0 * rel1) + 1e-9f;

    float tot = area;
    tot += __shfl_xor(tot, 1, 16);
    tot += __shfl_xor(tot, 2, 16);
    tot += __shfl_xor(tot, 4, 16);
    tot += __shfl_xor(tot, 8, 16);
    float arev = __shfl(area, (lane & 48) | (15 - k), 64);  // areas reversed over k
    float wgt  = arev / tot;

    if (lane < 16) {
        pix_ws [q0 * 16 + k] = pix;
        rel0_ws[q0 * 16 + k] = rel0;
        rel1_ws[q0 * 16 + k] = rel1;
        wgt_ws [q0 * 16 + k] = wgt;
        mi[wv][2 * k]     = rel0;
        mi[wv][2 * k + 1] = rel1;
    }
    if (lane == 0) mi[wv][32] = cell[q0 * 2 + 0] * 96.0f;
    __syncthreads();

    // meta layer 1: h[j] = relu(b_m1[j] + sum_i mi[i]*w_m1[i][j]),  j = lane
    float acc = b_m1[lane];
    #pragma unroll
    for (int i = 0; i < 33; i++) acc = fmaf(mi[wv][i], w_m1[i * 64 + lane], acc);
    h_ws[q0 * 64 + lane] = fmaxf(acc, 0.0f);
}

// ---------------------------------------------------------------------------
// K4: fused  mod-GEMM (64->1024) + gather/modulate + imnet (70->64->3) + blend
// 256 threads / block, 16 queries / block
// ---------------------------------------------------------------------------
__global__ __launch_bounds__(256) void fused_kernel(
    const float* __restrict__ inp, const float* __restrict__ cell,
    const float* __restrict__ feat_t, const float* __restrict__ w_m2t,
    const float* __restrict__ b_m2t, const float* __restrict__ h_ws,
    const int* __restrict__ pix_ws, const float* __restrict__ rel0_ws,
    const float* __restrict__ rel1_ws, const float* __restrict__ wgt_ws,
    const float* __restrict__ w_i1, const float* __restrict__ b_i1,
    const float* __restrict__ w_i2, const float* __restrict__ b_i2,
    float* __restrict__ out)
{
    __shared__ float h_lds[16 * 64];          // 4 KB
    __shared__ float x_lds[16 * 16 * 64];     // 64 KB
    __shared__ int   pix_lds[256];
    __shared__ float rel0_lds[256];
    __shared__ float rel1_lds[256];
    __shared__ float wgt_lds[256];
    __shared__ float rgb_lds[256 * 3];
    __shared__ float cellH_lds[16];
    __shared__ float wsum_lds[16];
    __shared__ float out_part[4][3];

    int t     = threadIdx.x;
    int qbase = blockIdx.x * 16;              // 16 consecutive global queries
    int b     = qbase >> 15;                  // Q = 32768
    int lane  = t & 63;
    int g     = t >> 6;                       // wave id 0..3

    // ---- prologue: stage per-query data ----
    #pragma unroll
    for (int i = 0; i < 4; i++) h_lds[t + 256 * i] = h_ws[qbase * 64 + t + 256 * i];
    pix_lds [t] = pix_ws [qbase * 16 + t];
    rel0_lds[t] = rel0_ws[qbase * 16 + t];
    rel1_lds[t] = rel1_ws[qbase * 16 + t];
    wgt_lds [t] = wgt_ws [qbase * 16 + t];
    {
        int pp = pix_ws[qbase * 16 + t];
        #pragma unroll
        for (int rr = 0; rr < 3; rr++)
            rgb_lds[t * 3 + rr] = inp[(b * 3 + rr) * HWSZ + pp];
    }
    if (t < 16) cellH_lds[t] = cell[(qbase + t) * 2] * 96.0f;
    __syncthreads();
    if (t < 16) {
        float s = 0.0f;
        for (int kk = 0; kk < 16; kk++) s += wgt_lds[t * 16 + kk];
        wsum_lds[t] = s;                      // ordered by post-mod barrier
    }

    // ---- mod phase: mod[q][kc] = b_m2t[kc] + sum_h h[q][h]*w_m2t[h][kc]
    // thread t covers kc = t + 256*i  ->  k = g + 4*i, c = lane
    float bm[4];
    #pragma unroll
    for (int i = 0; i < 4; i++) bm[i] = b_m2t[t + 256 * i];
    float acc[16][4];
    #pragma unroll
    for (int q = 0; q < 16; q++)
        #pragma unroll
        for (int i = 0; i < 4; i++) acc[q][i] = bm[i];

    for (int h = 0; h < 64; h += 2) {
        float w0[4], w1[4];
        #pragma unroll
        for (int i = 0; i < 4; i++) {
            w0[i] = w_m2t[ h      * 1024 + t + 256 * i];
            w1[i] = w_m2t[(h + 1) * 1024 + t + 256 * i];
        }
        #pragma unroll
        for (int q = 0; q < 16; q++) {
            float2 hv = *(const float2*)&h_lds[q * 64 + h];
            #pragma unroll
            for (int i = 0; i < 4; i++) acc[q][i] = fmaf(hv.x, w0[i], acc[q][i]);
            #pragma unroll
            for (int i = 0; i < 4; i++) acc[q][i] = fmaf(hv.y, w1[i], acc[q][i]);
        }
    }

    // ---- x = q_feat * mod -> x_lds[q][k][c] (bank = c mod 32: 2-way, free)
    #pragma unroll
    for (int q = 0; q < 16; q++) {
        #pragma unroll
        for (int i = 0; i < 4; i++) {
            int k  = g + 4 * i;
            int pp = pix_lds[q * 16 + k];
            float f = feat_t[(b * HWSZ + pp) * 64 + lane];
            x_lds[(q * 16 + k) * 64 + lane] = acc[q][i] * f;
        }
    }
    __syncthreads();

    // ---- imnet: per query, wave g handles k = g+4i; j = lane
    const int j = lane;
    float wr0 = w_i1[64 * 64 + j], wr1 = w_i1[65 * 64 + j], wr2 = w_i1[66 * 64 + j];
    float w67 = w_i1[67 * 64 + j], w68 = w_i1[68 * 64 + j], w69 = w_i1[69 * 64 + j];
    float wi2r0 = w_i2[j * 3 + 0], wi2r1 = w_i2[j * 3 + 1], wi2r2 = w_i2[j * 3 + 2];
    float bi1 = b_i1[j];

    for (int q = 0; q < 16; q++) {
        float hh[4];
        #pragma unroll
        for (int i = 0; i < 4; i++) hh[i] = bi1;
        #pragma unroll
        for (int cc = 0; cc < 16; cc++) {
            float wl0 = w_i1[(4 * cc + 0) * 64 + j];
            float wl1 = w_i1[(4 * cc + 1) * 64 + j];
            float wl2 = w_i1[(4 * cc + 2) * 64 + j];
            float wl3 = w_i1[(4 * cc + 3) * 64 + j];
            #pragma unroll
            for (int i = 0; i < 4; i++) {
                int k = g + 4 * i;
                const float4 xv = *(const float4*)&x_lds[(q * 16 + k) * 64 + 4 * cc];
                hh[i] = fmaf(xv.x, wl0, hh[i]);
                hh[i] = fmaf(xv.y, wl1, hh[i]);
                hh[i] = fmaf(xv.z, wl2, hh[i]);
                hh[i] = fmaf(xv.w, wl3, hh[i]);
            }
        }
        float gq = 0.0f;
        #pragma unroll
        for (int i = 0; i < 4; i++) {
            int k = g + 4 * i;
            float hv = hh[i];
            hv = fmaf(rgb_lds[(q * 16 + k) * 3 + 0], wr0, hv);
            hv = fmaf(rgb_lds[(q * 16 + k) * 3 + 1], wr1, hv);
            hv = fmaf(rgb_lds[(q * 16 + k) * 3 + 2], wr2, hv);
            hv = fmaf(rel0_lds[q * 16 + k], w67, hv);
            hv = fmaf(rel1_lds[q * 16 + k], w68, hv);
            hv = fmaf(cellH_lds[q],         w69, hv);
            hv = fmaxf(hv, 0.0f);                       // relu
            gq = fmaf(wgt_lds[q * 16 + k], hv, gq);     // fold area weight over k
        }
        float s0 = gq * wi2r0, s1 = gq * wi2r1, s2 = gq * wi2r2;
        #pragma unroll
        for (int m = 1; m < 64; m <<= 1) {
            s0 += __shfl_xor(s0, m, 64);
            s1 += __shfl_xor(s1, m, 64);
            s2 += __shfl_xor(s2, m, 64);
        }
        if (lane == 0) { out_part[g][0] = s0; out_part[g][1] = s1; out_part[g][2] = s2; }
        __syncthreads();
        if (t < 3) {
            float o = out_part[0][t] + out_part[1][t] + out_part[2][t] + out_part[3][t]
                    + b_i2[t] * wsum_lds[q];
            out[(qbase + q) * 3 + t] = o;
        }
        __syncthreads();
    }
}

// ---------------------------------------------------------------------------
extern "C" void kernel_launch(void* const* d_in, const int* in_sizes, int n_in,
                              void* d_out, int out_size, void* d_ws, size_t ws_size,
                              hipStream_t stream) {
    (void)in_sizes; (void)n_in; (void)out_size; (void)ws_size;
    const float* inp   = (const float*)d_in[0];
    const float* coord = (const float*)d_in[1];
    const float* cell  = (const float*)d_in[2];
    const float* w_enc = (const float*)d_in[3];
    const float* b_enc = (const float*)d_in[4];
    const float* w_m1  = (const float*)d_in[5];
    const float* b_m1  = (const float*)d_in[6];
    const float* w_m2  = (const float*)d_in[7];
    const float* b_m2  = (const float*)d_in[8];
    const float* w_i1  = (const float*)d_in[9];
    const float* b_i1  = (const float*)d_in[10];
    const float* w_i2  = (const float*)d_in[11];
    const float* b_i2  = (const float*)d_in[12];
    float* out = (float*)d_out;

    float* ws      = (float*)d_ws;
    float* feat_t  = ws;                         // B*HW*64      = 1,179,648 f
    float* w_m2t   = feat_t + 1179648;           // 65,536 f
    float* b_m2t   = w_m2t + 65536;              // 1,024 f
    float* h_ws    = b_m2t + 1024;               // B*Q*64       = 4,194,304 f
    int*   pix_ws  = (int*)(h_ws + 4194304);     // B*Q*16       = 1,048,576 i
    float* rel0_ws = (float*)(pix_ws + 1048576); // 1,048,576 f
    float* rel1_ws = rel0_ws + 1048576;          // 1,048,576 f
    float* wgt_ws  = rel1_ws + 1048576;          // 1,048,576 f
    // total ws use ~38.6 MB

    conv_kernel <<<4608, 256, 0, stream>>>(inp, w_enc, b_enc, feat_t);
    transpose_w2<<<260,  256, 0, stream>>>(w_m2, b_m2, w_m2t, b_m2t);
    prep_kernel <<<16384,256, 0, stream>>>(coord, cell, w_m1, b_m1, h_ws,
                                           pix_ws, rel0_ws, rel1_ws, wgt_ws);
    fused_kernel<<<4096, 256, 0, stream>>>(inp, cell, feat_t, w_m2t, b_m2t, h_ws,
                                           pix_ws, rel0_ws, rel1_ws, wgt_ws,
                                           w_i1, b_i1, w_i2, b_i2, out);
}